// Round 1
// baseline (777.339 us; speedup 1.0000x reference)
//
#include <hip/hip_runtime.h>

#define T 2048
#define D 1024
#define F 4096
#define E 8
#define NS 8
#define FS 512
#define SHB 5120      // shared-expert H base row (routed padded capacity)
#define NROWS 7168    // SHB + T
#define MT_MAX 56     // NROWS/128

typedef float floatx4 __attribute__((ext_vector_type(4)));
typedef short short8 __attribute__((ext_vector_type(8)));

__device__ __forceinline__ unsigned short f2bf(float f) {
  unsigned int u = __float_as_uint(f);
  u += 0x7FFF + ((u >> 16) & 1);   // RNE
  return (unsigned short)(u >> 16);
}

__device__ __forceinline__ void glds16(const void* g, void* l) {
  __builtin_amdgcn_global_load_lds(
      (const __attribute__((address_space(1))) void*)g,
      (__attribute__((address_space(3))) void*)l, 16, 0, 0);
}

// ---------------- gate: logits, softmax, top-2, x -> bf16 ----------------
__global__ void gate_kernel(const float* __restrict__ x, const float* __restrict__ gW,
                            unsigned short* __restrict__ xb, int* __restrict__ cnt,
                            int* __restrict__ list_tok, float* __restrict__ list_gate) {
  int t = blockIdx.x, tid = threadIdx.x;
  const float* xr = x + (size_t)t * D;
  float acc[E];
#pragma unroll
  for (int e = 0; e < E; ++e) acc[e] = 0.f;
  for (int d = tid; d < D; d += 256) {
    float xv = xr[d];
    xb[(size_t)t * D + d] = f2bf(xv);
#pragma unroll
    for (int e = 0; e < E; ++e) acc[e] += xv * gW[e * D + d];
  }
#pragma unroll
  for (int o = 32; o > 0; o >>= 1)
#pragma unroll
    for (int e = 0; e < E; ++e) acc[e] += __shfl_down(acc[e], o, 64);
  __shared__ float wred[4][E];
  int lane = tid & 63, wv = tid >> 6;
  if (lane == 0)
#pragma unroll
    for (int e = 0; e < E; ++e) wred[wv][e] = acc[e];
  __syncthreads();
  if (tid == 0) {
    float l[E];
#pragma unroll
    for (int e = 0; e < E; ++e) l[e] = wred[0][e] + wred[1][e] + wred[2][e] + wred[3][e];
    int i1 = 0; float m1 = l[0];
    for (int e = 1; e < E; ++e) if (l[e] > m1) { m1 = l[e]; i1 = e; }
    int i2 = -1; float m2 = -3.4e38f;
    for (int e = 0; e < E; ++e) if (e != i1 && l[e] > m2) { m2 = l[e]; i2 = e; }
    float s = 0.f, p[E];
#pragma unroll
    for (int e = 0; e < E; ++e) { p[e] = __expf(l[e] - m1); s += p[e]; }
    float inv = 1.f / s;
    int p1 = atomicAdd(&cnt[i1], 1);
    list_tok[i1 * T + p1] = t; list_gate[i1 * T + p1] = p[i1] * inv;
    int p2 = atomicAdd(&cnt[i2], 1);
    list_tok[i2 * T + p2] = t; list_gate[i2 * T + p2] = p[i2] * inv;
  }
}

// ---------------- offsets (1 thread): 128-aligned segment starts ----------------
__global__ void offsets_kernel(const int* __restrict__ cnt, int* __restrict__ off,
                               int* __restrict__ mt_expert) {
  if (threadIdx.x == 0 && blockIdx.x == 0) {
    int o = 0;
    for (int e = 0; e < E; ++e) { off[e] = o; o += (cnt[e] + 127) & ~127; }
    off[E] = o;
    for (int i = 0; i < MT_MAX; ++i) mt_expert[i] = -1;
    for (int e = 0; e < E; ++e) {
      int t0 = off[e] >> 7, nt = (cnt[e] + 127) >> 7;
      for (int i = 0; i < nt; ++i) mt_expert[t0 + i] = e;
    }
    for (int i = SHB >> 7; i < MT_MAX; ++i) mt_expert[i] = E;
  }
}

// ---------------- scatter: row maps + per-row scales ----------------
__global__ void scatter_kernel(const int* __restrict__ cnt, const int* __restrict__ off,
                               const int* __restrict__ list_tok, const float* __restrict__ list_gate,
                               int* __restrict__ tok_of_row, float* __restrict__ row_scale,
                               int* __restrict__ tok_rows, int* __restrict__ tk) {
  int idx = blockIdx.x * 256 + threadIdx.x;  // E*T
  int e = idx >> 11, i = idx & (T - 1);
  if (e < E && i < cnt[e]) {
    int row = off[e] + i;
    int t = list_tok[e * T + i];
    tok_of_row[row] = t;
    row_scale[row] = 0.5f * list_gate[e * T + i];
    int k = atomicAdd(&tk[t], 1);
    tok_rows[2 * t + k] = row;
  }
}

// ------- transpose+cast fp32 [R,C] -> bf16 B^T tiled [C/128][R/32][128][32] -------
__global__ void transpose_cast(const float* __restrict__ in, unsigned short* __restrict__ out,
                               int R, int C) {
  in += (size_t)blockIdx.z * R * C;
  out += (size_t)blockIdx.z * R * C;
  int r0 = blockIdx.y * 32, c0 = blockIdx.x * 32;
  __shared__ float tile[32][33];
  int tid = threadIdx.x;
#pragma unroll
  for (int p = 0; p < 4; ++p) {
    int idx = p * 256 + tid;
    int rl = idx >> 5, cl = idx & 31;
    tile[rl][cl] = in[(size_t)(r0 + rl) * C + c0 + cl];
  }
  __syncthreads();
  int Rt = R >> 5;
#pragma unroll
  for (int p = 0; p < 4; ++p) {
    int idx = p * 256 + tid;
    int cl = idx >> 5, rl = idx & 31;
    int c = c0 + cl, r = r0 + rl;
    size_t o = ((size_t)(c >> 7) * Rt + (r >> 5)) * 4096 + (size_t)(c & 127) * 32 + (r & 31);
    out[o] = f2bf(tile[rl][cl]);
  }
}

// ---------------- up GEMM: H = silu(A@W1) * (A@W3), grouped by expert ----------------
__global__ __launch_bounds__(256, 2) void up_gemm(
    const unsigned short* __restrict__ xb, const unsigned short* __restrict__ W1T,
    const unsigned short* __restrict__ W3T, const unsigned short* __restrict__ W1sT,
    const unsigned short* __restrict__ W3sT, const int* __restrict__ cnt,
    const int* __restrict__ off, const int* __restrict__ tok_of_row,
    unsigned short* __restrict__ Hb) {
  int e = blockIdx.z, mtile = blockIdx.y, ntile = blockIdx.x;
  int hbase;
  const unsigned short *B1, *B3;
  if (e < E) {
    int Me = cnt[e];
    if (mtile * 128 >= Me) return;
    hbase = off[e];
    B1 = W1T + (size_t)e * F * D;
    B3 = W3T + (size_t)e * F * D;
  } else {
    hbase = SHB;
    B1 = W1sT; B3 = W3sT;
  }
  __shared__ unsigned short Al[128 * 32];
  __shared__ unsigned short B1l[128 * 32];
  __shared__ unsigned short B3l[128 * 32];
  int tid = threadIdx.x;
  int lane = tid & 63, wv = tid >> 6, wm = wv >> 1, wn = wv & 1;
  int row16 = lane & 15, quad = lane >> 4;

  int ar = tid >> 1;                 // staged row 0..127 (2 threads/row)
  int lrow = mtile * 128 + ar;
  int srow = (e < E) ? tok_of_row[hbase + lrow] : lrow;
  const uint4* aptr = (const uint4*)(xb + (size_t)srow * D) + (tid & 1) * 2;
  uint4* alds = (uint4*)Al + ar * 4 + (tid & 1) * 2;

  const unsigned short* b1t = B1 + (size_t)ntile * (D / 32) * 4096;
  const unsigned short* b3t = B3 + (size_t)ntile * (D / 32) * 4096;

  floatx4 accg[4][4], accu[4][4];
#pragma unroll
  for (int i = 0; i < 4; ++i)
#pragma unroll
    for (int j = 0; j < 4; ++j) {
      accg[i][j] = (floatx4){0.f, 0.f, 0.f, 0.f};
      accu[i][j] = (floatx4){0.f, 0.f, 0.f, 0.f};
    }
  int lw = wv * 1024;  // wave LDS byte offset
  for (int kt = 0; kt < D / 32; ++kt) {
    uint4 av0 = aptr[0];
    uint4 av1 = aptr[1];
    const char* b1s = (const char*)(b1t + (size_t)kt * 4096);
    const char* b3s = (const char*)(b3t + (size_t)kt * 4096);
    glds16(b1s + tid * 16, (char*)B1l + lw);
    glds16(b1s + 4096 + tid * 16, (char*)B1l + 4096 + lw);
    glds16(b3s + tid * 16, (char*)B3l + lw);
    glds16(b3s + 4096 + tid * 16, (char*)B3l + 4096 + lw);
    alds[0] = av0; alds[1] = av1;
    __syncthreads();
    short8 af[4], b1f[4], b3f[4];
#pragma unroll
    for (int mi = 0; mi < 4; ++mi)
      af[mi] = *(const short8*)(Al + (wm * 64 + mi * 16 + row16) * 32 + quad * 8);
#pragma unroll
    for (int ni = 0; ni < 4; ++ni) {
      b1f[ni] = *(const short8*)(B1l + (wn * 64 + ni * 16 + row16) * 32 + quad * 8);
      b3f[ni] = *(const short8*)(B3l + (wn * 64 + ni * 16 + row16) * 32 + quad * 8);
    }
#pragma unroll
    for (int mi = 0; mi < 4; ++mi)
#pragma unroll
      for (int ni = 0; ni < 4; ++ni) {
        accg[mi][ni] = __builtin_amdgcn_mfma_f32_16x16x32_bf16(af[mi], b1f[ni], accg[mi][ni], 0, 0, 0);
        accu[mi][ni] = __builtin_amdgcn_mfma_f32_16x16x32_bf16(af[mi], b3f[ni], accu[mi][ni], 0, 0, 0);
      }
    aptr += 4;
    __syncthreads();
  }
  // epilogue: silu(g)*u -> bf16, H in tiled layout
#pragma unroll
  for (int mi = 0; mi < 4; ++mi)
#pragma unroll
    for (int ni = 0; ni < 4; ++ni)
#pragma unroll
      for (int r = 0; r < 4; ++r) {
        int lr = mtile * 128 + wm * 64 + mi * 16 + quad * 4 + r;
        int hrow = hbase + lr;
        int col = ntile * 128 + wn * 64 + ni * 16 + row16;
        float g = accg[mi][ni][r], u = accu[mi][ni][r];
        float h = g * u / (1.0f + __expf(-g));
        size_t o = ((size_t)(hrow >> 7) * 128 + (col >> 5)) * 4096 + (size_t)(hrow & 127) * 32 + (col & 31);
        Hb[o] = f2bf(h);
      }
}

// ---------------- down GEMM: O = (H @ W2) * row_scale ----------------
__global__ __launch_bounds__(256, 2) void down_gemm(
    const unsigned short* __restrict__ Hb, const unsigned short* __restrict__ W2T,
    const unsigned short* __restrict__ W2sT, const int* __restrict__ mt_expert,
    const float* __restrict__ row_scale, float* __restrict__ O) {
  int mt = blockIdx.y, ntile = blockIdx.x;
  int e = mt_expert[mt];
  if (e < 0) return;
  const unsigned short* Bt = ((e < E) ? (W2T + (size_t)e * D * F) : W2sT)
                             + (size_t)ntile * (F / 32) * 4096;
  const unsigned short* At = Hb + (size_t)mt * (F / 32) * 4096;
  __shared__ unsigned short Al[128 * 32];
  __shared__ unsigned short Bl[128 * 32];
  int tid = threadIdx.x;
  int lane = tid & 63, wv = tid >> 6, wm = wv >> 1, wn = wv & 1;
  int row16 = lane & 15, quad = lane >> 4;
  floatx4 acc[4][4];
#pragma unroll
  for (int i = 0; i < 4; ++i)
#pragma unroll
    for (int j = 0; j < 4; ++j) acc[i][j] = (floatx4){0.f, 0.f, 0.f, 0.f};
  int lw = wv * 1024;
  for (int kt = 0; kt < F / 32; ++kt) {
    const char* as = (const char*)(At + (size_t)kt * 4096);
    const char* bs = (const char*)(Bt + (size_t)kt * 4096);
    glds16(as + tid * 16, (char*)Al + lw);
    glds16(as + 4096 + tid * 16, (char*)Al + 4096 + lw);
    glds16(bs + tid * 16, (char*)Bl + lw);
    glds16(bs + 4096 + tid * 16, (char*)Bl + 4096 + lw);
    __syncthreads();
    short8 af[4], bf[4];
#pragma unroll
    for (int mi = 0; mi < 4; ++mi)
      af[mi] = *(const short8*)(Al + (wm * 64 + mi * 16 + row16) * 32 + quad * 8);
#pragma unroll
    for (int ni = 0; ni < 4; ++ni)
      bf[ni] = *(const short8*)(Bl + (wn * 64 + ni * 16 + row16) * 32 + quad * 8);
#pragma unroll
    for (int mi = 0; mi < 4; ++mi)
#pragma unroll
      for (int ni = 0; ni < 4; ++ni)
        acc[mi][ni] = __builtin_amdgcn_mfma_f32_16x16x32_bf16(af[mi], bf[ni], acc[mi][ni], 0, 0, 0);
    __syncthreads();
  }
#pragma unroll
  for (int mi = 0; mi < 4; ++mi)
#pragma unroll
    for (int ni = 0; ni < 4; ++ni)
#pragma unroll
      for (int r = 0; r < 4; ++r) {
        int grow = mt * 128 + wm * 64 + mi * 16 + quad * 4 + r;
        int col = ntile * 128 + wn * 64 + ni * 16 + row16;
        float scale = (grow < SHB) ? row_scale[grow] : 0.0625f;
        O[(size_t)grow * D + col] = acc[mi][ni][r] * scale;
      }
}

// ---------------- combine: out = O[r0] + O[r1] + O[shared] (scales baked in) ----------------
__global__ void combine_kernel(const float* __restrict__ O, const int* __restrict__ tok_rows,
                               float* __restrict__ out) {
  int idx = blockIdx.x * 256 + threadIdx.x;  // T * D/4
  int t = idx >> 8, c = idx & 255;
  int r0 = tok_rows[2 * t], r1 = tok_rows[2 * t + 1];
  const float4* O4 = (const float4*)O;
  float4 a = O4[(size_t)r0 * 256 + c];
  float4 b = O4[(size_t)r1 * 256 + c];
  float4 s = O4[((size_t)SHB + t) * 256 + c];
  float4 r;
  r.x = a.x + b.x + s.x;
  r.y = a.y + b.y + s.y;
  r.z = a.z + b.z + s.z;
  r.w = a.w + b.w + s.w;
  ((float4*)out)[idx] = r;
}

extern "C" void kernel_launch(void* const* d_in, const int* in_sizes, int n_in,
                              void* d_out, int out_size, void* d_ws, size_t ws_size,
                              hipStream_t stream) {
  (void)in_sizes; (void)n_in; (void)out_size; (void)ws_size;
  const float* x   = (const float*)d_in[0];
  const float* gW  = (const float*)d_in[1];
  const float* w1e = (const float*)d_in[2];
  const float* w3e = (const float*)d_in[3];
  const float* w2e = (const float*)d_in[4];
  const float* w1s = (const float*)d_in[5];
  const float* w3s = (const float*)d_in[6];
  const float* w2s = (const float*)d_in[7];
  float* out = (float*)d_out;

  char* w = (char*)d_ws;
  auto alloc = [&](size_t bytes) {
    char* p = w; w += (bytes + 255) & ~(size_t)255; return p;
  };
  unsigned short* xb   = (unsigned short*)alloc((size_t)T * D * 2);
  unsigned short* W1T  = (unsigned short*)alloc((size_t)E * F * D * 2);
  unsigned short* W3T  = (unsigned short*)alloc((size_t)E * F * D * 2);
  unsigned short* W2T  = (unsigned short*)alloc((size_t)E * D * F * 2);
  unsigned short* W1sT = (unsigned short*)alloc((size_t)F * D * 2);
  unsigned short* W3sT = (unsigned short*)alloc((size_t)F * D * 2);
  unsigned short* W2sT = (unsigned short*)alloc((size_t)D * F * 2);
  unsigned short* Hb   = (unsigned short*)alloc((size_t)NROWS * F * 2);
  float* Ob        = (float*)alloc((size_t)NROWS * D * 4);
  float* row_scale = (float*)alloc((size_t)SHB * 4);
  float* list_gate = (float*)alloc((size_t)E * T * 4);
  int* list_tok    = (int*)alloc((size_t)E * T * 4);
  int* tok_rows    = (int*)alloc((size_t)T * 2 * 4);
  int* offv        = (int*)alloc(16 * 4);
  int* mt_expert   = (int*)alloc(64 * 4);
  int* ctrl        = (int*)alloc((size_t)(8 + T + SHB) * 4);
  int* cnt = ctrl; int* tk = ctrl + 8; int* tok_of_row = ctrl + 8 + T;

  hipMemsetAsync(ctrl, 0, (size_t)(8 + T + SHB) * 4, stream);
  gate_kernel<<<T, 256, 0, stream>>>(x, gW, xb, cnt, list_tok, list_gate);
  offsets_kernel<<<1, 64, 0, stream>>>(cnt, offv, mt_expert);
  scatter_kernel<<<(E * T) / 256, 256, 0, stream>>>(cnt, offv, list_tok, list_gate,
                                                    tok_of_row, row_scale, tok_rows, tk);
  transpose_cast<<<dim3(F / 32, D / 32, E), 256, 0, stream>>>(w1e, W1T, D, F);
  transpose_cast<<<dim3(F / 32, D / 32, E), 256, 0, stream>>>(w3e, W3T, D, F);
  transpose_cast<<<dim3(D / 32, F / 32, E), 256, 0, stream>>>(w2e, W2T, F, D);
  transpose_cast<<<dim3(FS / 32, D / 32, NS), 256, 0, stream>>>(w1s, W1sT, D, FS);
  transpose_cast<<<dim3(FS / 32, D / 32, NS), 256, 0, stream>>>(w3s, W3sT, D, FS);
  transpose_cast<<<dim3(D / 32, F / 32, 1), 256, 0, stream>>>(w2s, W2sT, F, D);
  up_gemm<<<dim3(F / 128, 16, E + 1), 256, 0, stream>>>(xb, W1T, W3T, W1sT, W3sT,
                                                        cnt, offv, tok_of_row, Hb);
  down_gemm<<<dim3(D / 128, MT_MAX), 256, 0, stream>>>(Hb, W2T, W2sT, mt_expert, row_scale, Ob);
  combine_kernel<<<(T * D / 4) / 256, 256, 0, stream>>>(Ob, tok_rows, out);
}

// Round 2
// 745.227 us; speedup vs baseline: 1.0431x; 1.0431x over previous
//
#include <hip/hip_runtime.h>

#define T 2048
#define D 1024
#define F 4096
#define E 8
#define NS 8
#define FS 512
#define SHB 5120      // shared-expert H base row (routed padded capacity)
#define NROWS 7168    // SHB + T
#define MT_MAX 56     // NROWS/128

typedef float floatx4 __attribute__((ext_vector_type(4)));
typedef short short8 __attribute__((ext_vector_type(8)));

__device__ __forceinline__ unsigned short f2bf(float f) {
  unsigned int u = __float_as_uint(f);
  u += 0x7FFF + ((u >> 16) & 1);   // RNE
  return (unsigned short)(u >> 16);
}

__device__ __forceinline__ void glds16(const void* g, void* l) {
  __builtin_amdgcn_global_load_lds(
      (const __attribute__((address_space(1))) void*)g,
      (__attribute__((address_space(3))) void*)l, 16, 0, 0);
}

// ---------------- gate: logits, softmax, top-2, x -> bf16 ----------------
__global__ void gate_kernel(const float* __restrict__ x, const float* __restrict__ gW,
                            unsigned short* __restrict__ xb, int* __restrict__ cnt,
                            int* __restrict__ list_tok, float* __restrict__ list_gate) {
  int t = blockIdx.x, tid = threadIdx.x;
  const float* xr = x + (size_t)t * D;
  float acc[E];
#pragma unroll
  for (int e = 0; e < E; ++e) acc[e] = 0.f;
  for (int d = tid; d < D; d += 256) {
    float xv = xr[d];
    xb[(size_t)t * D + d] = f2bf(xv);
#pragma unroll
    for (int e = 0; e < E; ++e) acc[e] += xv * gW[e * D + d];
  }
#pragma unroll
  for (int o = 32; o > 0; o >>= 1)
#pragma unroll
    for (int e = 0; e < E; ++e) acc[e] += __shfl_down(acc[e], o, 64);
  __shared__ float wred[4][E];
  int lane = tid & 63, wv = tid >> 6;
  if (lane == 0)
#pragma unroll
    for (int e = 0; e < E; ++e) wred[wv][e] = acc[e];
  __syncthreads();
  if (tid == 0) {
    float l[E];
#pragma unroll
    for (int e = 0; e < E; ++e) l[e] = wred[0][e] + wred[1][e] + wred[2][e] + wred[3][e];
    int i1 = 0; float m1 = l[0];
    for (int e = 1; e < E; ++e) if (l[e] > m1) { m1 = l[e]; i1 = e; }
    int i2 = -1; float m2 = -3.4e38f;
    for (int e = 0; e < E; ++e) if (e != i1 && l[e] > m2) { m2 = l[e]; i2 = e; }
    float s = 0.f, p[E];
#pragma unroll
    for (int e = 0; e < E; ++e) { p[e] = __expf(l[e] - m1); s += p[e]; }
    float inv = 1.f / s;
    int p1 = atomicAdd(&cnt[i1], 1);
    list_tok[i1 * T + p1] = t; list_gate[i1 * T + p1] = p[i1] * inv;
    int p2 = atomicAdd(&cnt[i2], 1);
    list_tok[i2 * T + p2] = t; list_gate[i2 * T + p2] = p[i2] * inv;
  }
}

// ---------------- offsets (1 thread): 128-aligned segment starts ----------------
__global__ void offsets_kernel(const int* __restrict__ cnt, int* __restrict__ off,
                               int* __restrict__ mt_expert) {
  if (threadIdx.x == 0 && blockIdx.x == 0) {
    int o = 0;
    for (int e = 0; e < E; ++e) { off[e] = o; o += (cnt[e] + 127) & ~127; }
    off[E] = o;
    for (int i = 0; i < MT_MAX; ++i) mt_expert[i] = -1;
    for (int e = 0; e < E; ++e) {
      int t0 = off[e] >> 7, nt = (cnt[e] + 127) >> 7;
      for (int i = 0; i < nt; ++i) mt_expert[t0 + i] = e;
    }
    for (int i = SHB >> 7; i < MT_MAX; ++i) mt_expert[i] = E;
  }
}

// ---------------- scatter: row maps + per-row scales ----------------
__global__ void scatter_kernel(const int* __restrict__ cnt, const int* __restrict__ off,
                               const int* __restrict__ list_tok, const float* __restrict__ list_gate,
                               int* __restrict__ tok_of_row, float* __restrict__ row_scale,
                               int* __restrict__ tok_rows, int* __restrict__ tk) {
  int idx = blockIdx.x * 256 + threadIdx.x;  // E*T
  int e = idx >> 11, i = idx & (T - 1);
  if (e < E && i < cnt[e]) {
    int row = off[e] + i;
    int t = list_tok[e * T + i];
    tok_of_row[row] = t;
    row_scale[row] = 0.5f * list_gate[e * T + i];
    int k = atomicAdd(&tk[t], 1);
    tok_rows[2 * t + k] = row;
  }
}

// ------- transpose+cast fp32 [R,C] -> bf16 B^T tiled [C/128][R/32][128][32] -------
// 32r x 32c tile, 256 threads: 1 float4 read pass + 1 ushort4 write pass
__global__ void transpose_cast(const float* __restrict__ in, unsigned short* __restrict__ out,
                               int R, int C) {
  in += (size_t)blockIdx.z * R * C;
  out += (size_t)blockIdx.z * R * C;
  int r0 = blockIdx.y * 32, c0 = blockIdx.x * 32;
  __shared__ float tile[32][33];
  int tid = threadIdx.x;
  {
    int rl = tid >> 3, cl = (tid & 7) * 4;
    float4 v = *(const float4*)(in + (size_t)(r0 + rl) * C + c0 + cl);
    tile[rl][cl] = v.x; tile[rl][cl + 1] = v.y;
    tile[rl][cl + 2] = v.z; tile[rl][cl + 3] = v.w;
  }
  __syncthreads();
  {
    int cl = tid >> 3, rq = (tid & 7) * 4;
    int c = c0 + cl, r = r0 + rq;
    ushort4 v;
    v.x = f2bf(tile[rq][cl]);     v.y = f2bf(tile[rq + 1][cl]);
    v.z = f2bf(tile[rq + 2][cl]); v.w = f2bf(tile[rq + 3][cl]);
    int Rt = R >> 5;
    size_t o = ((size_t)(c >> 7) * Rt + (r >> 5)) * 4096 + (size_t)(c & 127) * 32 + (r & 31);
    *(ushort4*)(out + o) = v;
  }
}

// ---------------- up GEMM: H = silu(A@W1) * (A@W3), grouped by expert ----------------
// LDS XOR-swizzle: 16B slot j of row r holds global slot j ^ ((r>>1)&3)
__global__ __launch_bounds__(256, 2) void up_gemm(
    const unsigned short* __restrict__ xb, const unsigned short* __restrict__ W1T,
    const unsigned short* __restrict__ W3T, const unsigned short* __restrict__ W1sT,
    const unsigned short* __restrict__ W3sT, const int* __restrict__ mt_expert,
    const int* __restrict__ tok_of_row, unsigned short* __restrict__ Hb) {
  int mt = blockIdx.y, ntile = blockIdx.x;
  int e = mt_expert[mt];
  if (e < 0) return;
  const unsigned short *B1, *B3;
  if (e < E) {
    B1 = W1T + (size_t)e * F * D;
    B3 = W3T + (size_t)e * F * D;
  } else {
    B1 = W1sT; B3 = W3sT;
  }
  __shared__ unsigned short Al[128 * 32];
  __shared__ unsigned short B1l[128 * 32];
  __shared__ unsigned short B3l[128 * 32];
  int tid = threadIdx.x;
  int lane = tid & 63, wv = tid >> 6, wm = wv >> 1, wn = wv & 1;
  int row16 = lane & 15, quad = lane >> 4;
  int qsw8 = ((lane >> 4) ^ ((lane >> 1) & 3)) * 8;   // swizzled slot, in shorts
  int swzb = (tid & ~3) * 16 + (((tid & 3) ^ ((tid >> 3) & 3)) * 16);  // staging src byte off

  int ar = tid >> 1;                 // staged row 0..127 (2 threads/row)
  int hrow_s = mt * 128 + ar;
  int srow = (e < E) ? tok_of_row[hrow_s] : (hrow_s - SHB);
  int ja = (tid & 1) * 2;            // A global slot pair base
  int sa = (tid >> 2) & 3;           // A row swizzle = (ar>>1)&3
  const uint4* aptr = (const uint4*)(xb + (size_t)srow * D) + ja;
  uint4* alds0 = (uint4*)Al + ar * 4 + (ja ^ sa);
  uint4* alds1 = (uint4*)Al + ar * 4 + ((ja + 1) ^ sa);

  const unsigned short* b1t = B1 + (size_t)ntile * (D / 32) * 4096;
  const unsigned short* b3t = B3 + (size_t)ntile * (D / 32) * 4096;

  floatx4 accg[4][4], accu[4][4];
#pragma unroll
  for (int i = 0; i < 4; ++i)
#pragma unroll
    for (int j = 0; j < 4; ++j) {
      accg[i][j] = (floatx4){0.f, 0.f, 0.f, 0.f};
      accu[i][j] = (floatx4){0.f, 0.f, 0.f, 0.f};
    }
  int lw = wv * 1024;  // wave LDS byte offset
  for (int kt = 0; kt < D / 32; ++kt) {
    uint4 av0 = aptr[0];
    uint4 av1 = aptr[1];
    const char* b1s = (const char*)(b1t + (size_t)kt * 4096);
    const char* b3s = (const char*)(b3t + (size_t)kt * 4096);
    glds16(b1s + swzb, (char*)B1l + lw);
    glds16(b1s + 4096 + swzb, (char*)B1l + 4096 + lw);
    glds16(b3s + swzb, (char*)B3l + lw);
    glds16(b3s + 4096 + swzb, (char*)B3l + 4096 + lw);
    alds0[0] = av0; alds1[0] = av1;
    __syncthreads();
    short8 af[4], b1f[4], b3f[4];
#pragma unroll
    for (int mi = 0; mi < 4; ++mi)
      af[mi] = *(const short8*)(Al + (wm * 64 + mi * 16 + row16) * 32 + qsw8);
#pragma unroll
    for (int ni = 0; ni < 4; ++ni) {
      b1f[ni] = *(const short8*)(B1l + (wn * 64 + ni * 16 + row16) * 32 + qsw8);
      b3f[ni] = *(const short8*)(B3l + (wn * 64 + ni * 16 + row16) * 32 + qsw8);
    }
#pragma unroll
    for (int mi = 0; mi < 4; ++mi)
#pragma unroll
      for (int ni = 0; ni < 4; ++ni) {
        accg[mi][ni] = __builtin_amdgcn_mfma_f32_16x16x32_bf16(af[mi], b1f[ni], accg[mi][ni], 0, 0, 0);
        accu[mi][ni] = __builtin_amdgcn_mfma_f32_16x16x32_bf16(af[mi], b3f[ni], accu[mi][ni], 0, 0, 0);
      }
    aptr += 4;
    __syncthreads();
  }
  // epilogue: silu(g)*u -> bf16, H in tiled layout
#pragma unroll
  for (int mi = 0; mi < 4; ++mi)
#pragma unroll
    for (int ni = 0; ni < 4; ++ni)
#pragma unroll
      for (int r = 0; r < 4; ++r) {
        int hrow = mt * 128 + wm * 64 + mi * 16 + quad * 4 + r;
        int col = ntile * 128 + wn * 64 + ni * 16 + row16;
        float g = accg[mi][ni][r], u = accu[mi][ni][r];
        float h = g * u / (1.0f + __expf(-g));
        size_t o = ((size_t)(hrow >> 7) * 128 + (col >> 5)) * 4096 + (size_t)(hrow & 127) * 32 + (col & 31);
        Hb[o] = f2bf(h);
      }
}

// ---------------- down GEMM: O = (H @ W2) * row_scale, split-K x2 ----------------
__global__ __launch_bounds__(256, 2) void down_gemm(
    const unsigned short* __restrict__ Hb, const unsigned short* __restrict__ W2T,
    const unsigned short* __restrict__ W2sT, const int* __restrict__ mt_expert,
    const float* __restrict__ row_scale, float* __restrict__ O) {
  int mt = blockIdx.y, ntile = blockIdx.x, kz = blockIdx.z;
  int e = mt_expert[mt];
  if (e < 0) return;
  const unsigned short* Bt = ((e < E) ? (W2T + (size_t)e * D * F) : W2sT)
                             + (size_t)ntile * (F / 32) * 4096;
  const unsigned short* At = Hb + (size_t)mt * (F / 32) * 4096;
  O += (size_t)kz * NROWS * D;
  __shared__ unsigned short Al[128 * 32];
  __shared__ unsigned short Bl[128 * 32];
  int tid = threadIdx.x;
  int lane = tid & 63, wv = tid >> 6, wm = wv >> 1, wn = wv & 1;
  int row16 = lane & 15, quad = lane >> 4;
  int qsw8 = ((lane >> 4) ^ ((lane >> 1) & 3)) * 8;
  int swzb = (tid & ~3) * 16 + (((tid & 3) ^ ((tid >> 3) & 3)) * 16);
  floatx4 acc[4][4];
#pragma unroll
  for (int i = 0; i < 4; ++i)
#pragma unroll
    for (int j = 0; j < 4; ++j) acc[i][j] = (floatx4){0.f, 0.f, 0.f, 0.f};
  int lw = wv * 1024;
  for (int kt = kz * 64; kt < kz * 64 + 64; ++kt) {
    const char* as = (const char*)(At + (size_t)kt * 4096);
    const char* bs = (const char*)(Bt + (size_t)kt * 4096);
    glds16(as + swzb, (char*)Al + lw);
    glds16(as + 4096 + swzb, (char*)Al + 4096 + lw);
    glds16(bs + swzb, (char*)Bl + lw);
    glds16(bs + 4096 + swzb, (char*)Bl + 4096 + lw);
    __syncthreads();
    short8 af[4], bf[4];
#pragma unroll
    for (int mi = 0; mi < 4; ++mi)
      af[mi] = *(const short8*)(Al + (wm * 64 + mi * 16 + row16) * 32 + qsw8);
#pragma unroll
    for (int ni = 0; ni < 4; ++ni)
      bf[ni] = *(const short8*)(Bl + (wn * 64 + ni * 16 + row16) * 32 + qsw8);
#pragma unroll
    for (int mi = 0; mi < 4; ++mi)
#pragma unroll
      for (int ni = 0; ni < 4; ++ni)
        acc[mi][ni] = __builtin_amdgcn_mfma_f32_16x16x32_bf16(af[mi], bf[ni], acc[mi][ni], 0, 0, 0);
    __syncthreads();
  }
#pragma unroll
  for (int mi = 0; mi < 4; ++mi)
#pragma unroll
    for (int ni = 0; ni < 4; ++ni)
#pragma unroll
      for (int r = 0; r < 4; ++r) {
        int grow = mt * 128 + wm * 64 + mi * 16 + quad * 4 + r;
        int col = ntile * 128 + wn * 64 + ni * 16 + row16;
        float scale = (grow < SHB) ? row_scale[grow] : 0.0625f;
        O[(size_t)grow * D + col] = acc[mi][ni][r] * scale;
      }
}

// ---------------- combine: out = sum over {r0, r1, shared} x {2 k-halves} ----------------
__global__ void combine_kernel(const float* __restrict__ O, const int* __restrict__ tok_rows,
                               float* __restrict__ out) {
  int idx = blockIdx.x * 256 + threadIdx.x;  // T * D/4
  int t = idx >> 8, c = idx & 255;
  int r0 = tok_rows[2 * t], r1 = tok_rows[2 * t + 1];
  const float4* O4 = (const float4*)O;
  const size_t HLF = (size_t)NROWS * 256;
  float4 a = O4[(size_t)r0 * 256 + c];
  float4 b = O4[(size_t)r1 * 256 + c];
  float4 s = O4[((size_t)SHB + t) * 256 + c];
  float4 a2 = O4[HLF + (size_t)r0 * 256 + c];
  float4 b2 = O4[HLF + (size_t)r1 * 256 + c];
  float4 s2 = O4[HLF + ((size_t)SHB + t) * 256 + c];
  float4 r;
  r.x = a.x + b.x + s.x + a2.x + b2.x + s2.x;
  r.y = a.y + b.y + s.y + a2.y + b2.y + s2.y;
  r.z = a.z + b.z + s.z + a2.z + b2.z + s2.z;
  r.w = a.w + b.w + s.w + a2.w + b2.w + s2.w;
  ((float4*)out)[idx] = r;
}

extern "C" void kernel_launch(void* const* d_in, const int* in_sizes, int n_in,
                              void* d_out, int out_size, void* d_ws, size_t ws_size,
                              hipStream_t stream) {
  (void)in_sizes; (void)n_in; (void)out_size; (void)ws_size;
  const float* x   = (const float*)d_in[0];
  const float* gW  = (const float*)d_in[1];
  const float* w1e = (const float*)d_in[2];
  const float* w3e = (const float*)d_in[3];
  const float* w2e = (const float*)d_in[4];
  const float* w1s = (const float*)d_in[5];
  const float* w3s = (const float*)d_in[6];
  const float* w2s = (const float*)d_in[7];
  float* out = (float*)d_out;

  char* w = (char*)d_ws;
  auto alloc = [&](size_t bytes) {
    char* p = w; w += (bytes + 255) & ~(size_t)255; return p;
  };
  unsigned short* xb   = (unsigned short*)alloc((size_t)T * D * 2);
  unsigned short* W1T  = (unsigned short*)alloc((size_t)E * F * D * 2);
  unsigned short* W3T  = (unsigned short*)alloc((size_t)E * F * D * 2);
  unsigned short* W2T  = (unsigned short*)alloc((size_t)E * D * F * 2);
  unsigned short* W1sT = (unsigned short*)alloc((size_t)F * D * 2);
  unsigned short* W3sT = (unsigned short*)alloc((size_t)F * D * 2);
  unsigned short* W2sT = (unsigned short*)alloc((size_t)D * F * 2);
  unsigned short* Hb   = (unsigned short*)alloc((size_t)NROWS * F * 2);
  float* Ob        = (float*)alloc((size_t)2 * NROWS * D * 4);
  float* row_scale = (float*)alloc((size_t)SHB * 4);
  float* list_gate = (float*)alloc((size_t)E * T * 4);
  int* list_tok    = (int*)alloc((size_t)E * T * 4);
  int* tok_rows    = (int*)alloc((size_t)T * 2 * 4);
  int* offv        = (int*)alloc(16 * 4);
  int* mt_expert   = (int*)alloc(64 * 4);
  int* ctrl        = (int*)alloc((size_t)(8 + T + SHB) * 4);
  int* cnt = ctrl; int* tk = ctrl + 8; int* tok_of_row = ctrl + 8 + T;

  hipMemsetAsync(ctrl, 0, (size_t)(8 + T + SHB) * 4, stream);
  gate_kernel<<<T, 256, 0, stream>>>(x, gW, xb, cnt, list_tok, list_gate);
  offsets_kernel<<<1, 64, 0, stream>>>(cnt, offv, mt_expert);
  scatter_kernel<<<(E * T) / 256, 256, 0, stream>>>(cnt, offv, list_tok, list_gate,
                                                    tok_of_row, row_scale, tok_rows, tk);
  transpose_cast<<<dim3(F / 32, D / 32, E), 256, 0, stream>>>(w1e, W1T, D, F);
  transpose_cast<<<dim3(F / 32, D / 32, E), 256, 0, stream>>>(w3e, W3T, D, F);
  transpose_cast<<<dim3(D / 32, F / 32, E), 256, 0, stream>>>(w2e, W2T, F, D);
  transpose_cast<<<dim3(FS / 32, D / 32, NS), 256, 0, stream>>>(w1s, W1sT, D, FS);
  transpose_cast<<<dim3(FS / 32, D / 32, NS), 256, 0, stream>>>(w3s, W3sT, D, FS);
  transpose_cast<<<dim3(D / 32, F / 32, 1), 256, 0, stream>>>(w2s, W2sT, F, D);
  up_gemm<<<dim3(F / 128, MT_MAX), 256, 0, stream>>>(xb, W1T, W3T, W1sT, W3sT,
                                                     mt_expert, tok_of_row, Hb);
  down_gemm<<<dim3(D / 128, MT_MAX, 2), 256, 0, stream>>>(Hb, W2T, W2sT, mt_expert, row_scale, Ob);
  combine_kernel<<<(T * D / 4) / 256, 256, 0, stream>>>(Ob, tok_rows, out);
}